// Round 1
// baseline (163.515 us; speedup 1.0000x reference)
//
#include <hip/hip_runtime.h>
#include <math.h>

#define WAVE 64
#define KPOOL 16
#define WAVES_PER_BLOCK 4

// Wave-parallel lower_bound: first index i in sorted a[0..n) with a[i] >= key.
// 64-ary search: ~5 probe rounds for n=16.7M instead of 24 scalar steps.
__device__ __forceinline__ int lower_bound_wave(const int* __restrict__ a, int n,
                                                int key, int lane) {
  int lo = 0, hi = n;  // invariant: a[lo-1] < key <= a[hi]  (virtual -inf/+inf)
  while (hi - lo > WAVE) {
    unsigned len = (unsigned)(hi - lo);  // len*(lane+1) <= 2^24 * 64 = 2^30, fits u32
    bool lt = false;
    if (lane < 63) {
      int idx = lo + (int)((len * (unsigned)(lane + 1)) >> 6);  // idx < hi
      lt = (a[idx] < key);
    }
    unsigned long long m = __ballot(lt);
    int t = __popcll(m);  // prefix property: lanes 0..t-1 true
    int nlo = (t == 0) ? lo : lo + (int)((len * (unsigned)t) >> 6);
    int nhi = (t == 63) ? hi : lo + (int)((len * (unsigned)(t + 1)) >> 6);
    lo = nlo;
    hi = nhi;
  }
  // final linear step over <=64 candidates
  int idx = lo + lane;
  bool lt = (idx < hi) && (a[idx] < key);
  unsigned long long m = __ballot(lt);
  return lo + __popcll(m);
}

__global__ __launch_bounds__(WAVE * WAVES_PER_BLOCK)
void sortpool_topk_kernel(const float* __restrict__ Y,
                          const float* __restrict__ W,
                          const int* __restrict__ emap,
                          float* __restrict__ out,
                          int total, int n) {
  const int lane = threadIdx.x & (WAVE - 1);
  const int g = blockIdx.x * WAVES_PER_BLOCK + (threadIdx.x >> 6);
  if (g >= n) return;

  // ---- segment bounds via wave-parallel binary search on sorted e_map ----
  const int start = lower_bound_wave(emap, total, g, lane);
  const int end = lower_bound_wave(emap, total, g + 1, lane);
  const int len = end - start;

  // ---- softmax(W) over 16 entries; lane k (k<16) holds wn[k] ----
  float w = (lane < KPOOL) ? W[lane] : -INFINITY;
  float wm = w;
#pragma unroll
  for (int d = 1; d < KPOOL; d <<= 1) wm = fmaxf(wm, __shfl_xor(wm, d));
  float e = (lane < KPOOL) ? expf(w - wm) : 0.0f;
  float s = e;
#pragma unroll
  for (int d = 1; d < KPOOL; d <<= 1) s += __shfl_xor(s, d);
  const float wn = e / s;  // valid in lanes 0..15

  // ---- iterative top-K selection with (threshold t, taken-count c) ----
  // Exactly reproduces top_k-with-duplicates semantics: each round emits the
  // next value of the descending sorted multiset.
  float t = INFINITY;
  int c = 0;
  float result = 0.0f;

  if (len <= KPOOL * WAVE) {
    // fast path: whole segment in registers (16 regs/lane covers len<=1024;
    // actual max segment ~350 for Poisson(256))
    float vals[KPOOL];
#pragma unroll
    for (int j = 0; j < KPOOL; j++) {
      int idx = start + lane + j * WAVE;
      vals[j] = (idx < end) ? Y[idx] : -INFINITY;
    }
#pragma unroll 1
    for (int k = 0; k < KPOOL; k++) {
      int cnt = 0;
      float mx = -INFINITY;
#pragma unroll
      for (int j = 0; j < KPOOL; j++) {
        if (j * WAVE >= len) break;  // wave-uniform early exit
        float v = vals[j];
        if (v == t) cnt++;
        if (v < t) mx = fmaxf(mx, v);
      }
#pragma unroll
      for (int d = 1; d < WAVE; d <<= 1) {
        cnt += __shfl_xor(cnt, d);
        mx = fmaxf(mx, __shfl_xor(mx, d));
      }
      float next;
      if (cnt > c) {  // another copy of the current max value remains
        next = t;
        c = c + 1;
      } else {  // descend to next strictly-smaller value
        next = mx;
        t = mx;
        c = 1;
      }
      float wk = __shfl(wn, k);
      if (next > -INFINITY) result += wk * next;  // -inf (exhausted) -> 0
    }
  } else {
    // exact fallback for absurdly large segments: 16 passes over global memory
#pragma unroll 1
    for (int k = 0; k < KPOOL; k++) {
      int cnt = 0;
      float mx = -INFINITY;
      for (int i = start + lane; i < end; i += WAVE) {
        float v = Y[i];
        if (v == t) cnt++;
        if (v < t) mx = fmaxf(mx, v);
      }
#pragma unroll
      for (int d = 1; d < WAVE; d <<= 1) {
        cnt += __shfl_xor(cnt, d);
        mx = fmaxf(mx, __shfl_xor(mx, d));
      }
      float next;
      if (cnt > c) {
        next = t;
        c = c + 1;
      } else {
        next = mx;
        t = mx;
        c = 1;
      }
      float wk = __shfl(wn, k);
      if (next > -INFINITY) result += wk * next;
    }
  }

  if (lane == 0) out[g] = result;
}

extern "C" void kernel_launch(void* const* d_in, const int* in_sizes, int n_in,
                              void* d_out, int out_size, void* d_ws, size_t ws_size,
                              hipStream_t stream) {
  const float* Y = (const float*)d_in[0];     // [TOTAL] (squeezed [TOTAL,1])
  const float* W = (const float*)d_in[1];     // [16]
  const int* emap = (const int*)d_in[2];      // [TOTAL], sorted
  // d_in[3] = v_count: only its length matters
  const int total = in_sizes[0];
  const int n = in_sizes[3];
  float* out = (float*)d_out;                 // [N] float32

  const int blocks = (n + WAVES_PER_BLOCK - 1) / WAVES_PER_BLOCK;
  sortpool_topk_kernel<<<blocks, WAVE * WAVES_PER_BLOCK, 0, stream>>>(
      Y, W, emap, out, total, n);
}

// Round 2
// 54.588 us; speedup vs baseline: 2.9955x; 2.9955x over previous
//
#include <hip/hip_runtime.h>
#include <math.h>

#define KPOOL 16
#define SPLIT 4  // threads cooperating on one graph

// Branchless insertion of v into a descending-sorted 16-register list.
// 2 VALU per slot; preserves multiset (ties handled exactly like top_k).
__device__ __forceinline__ void insert16(float (&t)[KPOOL], float v) {
#pragma unroll
  for (int s = 0; s < KPOOL; ++s) {
    float mx = fmaxf(t[s], v);
    v = fminf(t[s], v);
    t[s] = mx;
  }
}

// Merge this lane's descending sorted-16 with partner lane's (lane ^ dist):
// keep the top-16 of the union, sorted descending. Classic bitonic top-k:
// C[i] = max(A[i], B[15-i]) contains the top-16 multiset and is bitonic
// (valley); 4 half-cleaner stages restore descending order.
__device__ __forceinline__ void merge_partner(float (&t)[KPOOL], int dist) {
  float c[KPOOL];
#pragma unroll
  for (int i = 0; i < KPOOL; ++i) {
    float o = __shfl_xor(t[KPOOL - 1 - i], dist);
    c[i] = fmaxf(t[i], o);
  }
#pragma unroll
  for (int s = 8; s >= 1; s >>= 1) {
#pragma unroll
    for (int i = 0; i < KPOOL; ++i) {
      if ((i & s) == 0) {
        float hi = fmaxf(c[i], c[i + s]);
        float lo = fminf(c[i], c[i + s]);
        c[i] = hi;
        c[i + s] = lo;
      }
    }
  }
#pragma unroll
  for (int i = 0; i < KPOOL; ++i) t[i] = c[i];
}

__device__ __forceinline__ int lower_bound_scalar(const int* __restrict__ a,
                                                  int nn, int key) {
  int lo = 0, hi = nn;
  while (lo < hi) {
    int mid = (lo + hi) >> 1;
    if (a[mid] < key) lo = mid + 1;
    else hi = mid;
  }
  return lo;
}

// starts[g] = first index i with emap[i] >= g, for g in [0, n]. starts[n]=total.
__global__ __launch_bounds__(256)
void boundary_kernel(const int* __restrict__ emap, int total, int n,
                     int* __restrict__ starts) {
  int g = blockIdx.x * 256 + threadIdx.x;
  if (g > n) return;
  starts[g] = lower_bound_scalar(emap, total, g);
}

__global__ __launch_bounds__(256)
void sortpool_main(const float* __restrict__ Y, const float* __restrict__ W,
                   const int* __restrict__ starts, const int* __restrict__ emap,
                   float* __restrict__ out, int total, int n) {
  const int tid = blockIdx.x * 256 + threadIdx.x;
  const int g = tid >> 2;   // graph id; 4 consecutive lanes share a graph
  const int q = tid & 3;    // quarter id
  if (g >= n) return;

  int s0, s1;
  if (starts) {
    s0 = starts[g];
    s1 = starts[g + 1];
  } else {  // fallback if ws too small: per-thread binary search
    s0 = lower_bound_scalar(emap, total, g);
    s1 = lower_bound_scalar(emap, total, g + 1);
  }
  const int len = s1 - s0;
  int a = s0 + ((len * q) >> 2);
  int b = s0 + ((len * (q + 1)) >> 2);

  float t[KPOOL];
#pragma unroll
  for (int i = 0; i < KPOOL; ++i) t[i] = -INFINITY;

  // ---- scan quarter [a, b): sorted-insert every element ----
  int i = a;
  while (i < b && (i & 3)) { insert16(t, Y[i]); ++i; }  // align to 16B
  for (; i + 8 <= b; i += 8) {
    float4 v0 = *reinterpret_cast<const float4*>(Y + i);
    float4 v1 = *reinterpret_cast<const float4*>(Y + i + 4);
    insert16(t, v0.x); insert16(t, v0.y); insert16(t, v0.z); insert16(t, v0.w);
    insert16(t, v1.x); insert16(t, v1.y); insert16(t, v1.z); insert16(t, v1.w);
  }
  if (i + 4 <= b) {
    float4 v0 = *reinterpret_cast<const float4*>(Y + i);
    insert16(t, v0.x); insert16(t, v0.y); insert16(t, v0.z); insert16(t, v0.w);
    i += 4;
  }
  while (i < b) { insert16(t, Y[i]); ++i; }

  // ---- combine the 4 quarters' sorted top-16 lists ----
  merge_partner(t, 1);
  merge_partner(t, 2);

  // ---- softmax(W) dot top-16 (uniform across threads; store from q==0) ----
  float wv[KPOOL];
#pragma unroll
  for (int k = 0; k < KPOOL; ++k) wv[k] = W[k];
  float wm = wv[0];
#pragma unroll
  for (int k = 1; k < KPOOL; ++k) wm = fmaxf(wm, wv[k]);
  float wsum = 0.0f;
#pragma unroll
  for (int k = 0; k < KPOOL; ++k) {
    wv[k] = expf(wv[k] - wm);
    wsum += wv[k];
  }
  const float inv = 1.0f / wsum;
  float res = 0.0f;
#pragma unroll
  for (int k = 0; k < KPOOL; ++k) {
    float v = t[k];
    res += (v > -INFINITY) ? v * (wv[k] * inv) : 0.0f;  // -inf (exhausted) -> 0
  }

  if (q == 0) out[g] = res;
}

extern "C" void kernel_launch(void* const* d_in, const int* in_sizes, int n_in,
                              void* d_out, int out_size, void* d_ws, size_t ws_size,
                              hipStream_t stream) {
  const float* Y = (const float*)d_in[0];   // [TOTAL]
  const float* W = (const float*)d_in[1];   // [16]
  const int* emap = (const int*)d_in[2];    // [TOTAL], sorted
  const int total = in_sizes[0];
  const int n = in_sizes[3];                // len(v_count)
  float* out = (float*)d_out;               // [N] float32

  int* starts = (int*)d_ws;
  const bool use_ws = (ws_size >= (size_t)(n + 1) * sizeof(int));

  if (use_ws) {
    int nb = (n + 1 + 255) / 256;
    boundary_kernel<<<nb, 256, 0, stream>>>(emap, total, n, starts);
  }

  long long threads = (long long)n * SPLIT;
  int blocks = (int)((threads + 255) / 256);
  sortpool_main<<<blocks, 256, 0, stream>>>(Y, W, use_ws ? starts : nullptr,
                                            emap, out, total, n);
}